// Round 10
// baseline (551.482 us; speedup 1.0000x reference)
//
#include <hip/hip_runtime.h>
#include <hip/hip_bf16.h>
#include <math.h>

#define NEG_ATT 0.2f
#define NEG_ACT 0.01f

__device__ __forceinline__ float lrelu(float v, float s) { return v >= 0.f ? v : s * v; }

// round-to-nearest-even f32 -> bf16 (top 16 bits)
__device__ __forceinline__ unsigned int rne_bf16(float f) {
    unsigned int u = __float_as_uint(f);
    return (u + 0x7FFFu + ((u >> 16) & 1u)) >> 16;
}
// unpack u32 (2 bf16) -> 2 floats
__device__ __forceinline__ float2 bf2_to_f2(unsigned int v) {
    return make_float2(__uint_as_float(v << 16), __uint_as_float(v & 0xFFFF0000u));
}

// ==================== CSR build ====================
__global__ __launch_bounds__(256) void k_hist(
    const int* __restrict__ dst, int* __restrict__ counts, int E, int Etot)
{
    int e = blockIdx.x * 256 + threadIdx.x;
    if (e >= Etot) return;
    int d = (e < E) ? dst[e] : e - E;   // self-loops appended as edges [E, E+N)
    atomicAdd(&counts[d], 1);
}

__global__ __launch_bounds__(1024) void k_bsum(
    const int* __restrict__ counts, int* __restrict__ bsum, int N)
{
    int i = blockIdx.x * 1024 + threadIdx.x;
    int v = (i < N) ? counts[i] : 0;
    #pragma unroll
    for (int m = 1; m < 64; m <<= 1) v += __shfl_xor(v, m, 64);
    __shared__ int ws[16];
    int lane = threadIdx.x & 63, w = threadIdx.x >> 6;
    if (lane == 0) ws[w] = v;
    __syncthreads();
    if (threadIdx.x == 0) {
        int t = 0;
        #pragma unroll
        for (int k = 0; k < 16; ++k) t += ws[k];
        bsum[blockIdx.x] = t;
    }
}

__global__ __launch_bounds__(1024) void k_scan(
    const int* __restrict__ in, int* __restrict__ out, int N)
{
    __shared__ int wsum[16];
    __shared__ int carry_s;
    const int tid = threadIdx.x;
    const int lane = tid & 63, w = tid >> 6;
    if (tid == 0) carry_s = 0;
    __syncthreads();
    for (int base = 0; base < N; base += 1024) {
        int i = base + tid;
        int v = (i < N) ? in[i] : 0;
        int incl = v;
        #pragma unroll
        for (int s = 1; s < 64; s <<= 1) {
            int t = __shfl_up(incl, s, 64);
            if (lane >= s) incl += t;
        }
        if (lane == 63) wsum[w] = incl;
        __syncthreads();
        int woff = 0;
        #pragma unroll
        for (int k = 0; k < 16; ++k) woff += (k < w) ? wsum[k] : 0;
        int carry = carry_s;
        if (i < N) out[i] = carry + woff + incl - v;   // exclusive
        __syncthreads();
        if (tid == 1023) carry_s = carry + woff + incl;
        __syncthreads();
    }
}

__global__ __launch_bounds__(1024) void k_scanadd(
    const int* __restrict__ counts, const int* __restrict__ boff,
    int* __restrict__ cursor, int N)
{
    const int tid = threadIdx.x;
    const int i = blockIdx.x * 1024 + tid;
    int v = (i < N) ? counts[i] : 0;
    int incl = v;
    const int lane = tid & 63, w = tid >> 6;
    #pragma unroll
    for (int s = 1; s < 64; s <<= 1) {
        int t = __shfl_up(incl, s, 64);
        if (lane >= s) incl += t;
    }
    __shared__ int ws[16];
    if (lane == 63) ws[w] = incl;
    __syncthreads();
    int woff = 0;
    #pragma unroll
    for (int k = 0; k < 16; ++k) woff += (k < w) ? ws[k] : 0;
    if (i < N) cursor[i] = boff[blockIdx.x] + woff + incl - v;
}

__global__ __launch_bounds__(256) void k_scatter(
    const int* __restrict__ src, const int* __restrict__ dst,
    int* __restrict__ cursor, int* __restrict__ csr, int E, int Etot)
{
    int e = blockIdx.x * 256 + threadIdx.x;
    if (e >= Etot) return;
    int s, d;
    if (e < E) { s = src[e]; d = dst[e]; } else { s = e - E; d = s; }
    int pos = atomicAdd(&cursor[d], 1);
    csr[pos] = s;
}

// ==================== K1: h1 = x @ W1 (+ attention dots); h1 stored bf16 ====================
__global__ __launch_bounds__(256) void k_gemm1(
    const float* __restrict__ x, const float* __restrict__ W,
    const float* __restrict__ a_src, const float* __restrict__ a_dst,
    unsigned int* __restrict__ h1b, float* __restrict__ as1, float* __restrict__ ad1, int N)
{
    __shared__ float Wl[128 * 128];
    const int tid = threadIdx.x;
    {
        float4* Wl4 = (float4*)Wl;
        const float4* W4 = (const float4*)W;
        #pragma unroll
        for (int i = 0; i < 16; ++i) Wl4[tid + i * 256] = W4[tid + i * 256];
    }
    __syncthreads();

    const int nl = tid & 31, hg = tid >> 5;
    int n = blockIdx.x * 32 + nl;
    if (n >= N) n = N - 1;

    const float4* xrow = (const float4*)(x + (size_t)n * 128);
    float acc[16];
    #pragma unroll
    for (int j = 0; j < 16; ++j) acc[j] = 0.f;

    for (int k4 = 0; k4 < 32; ++k4) {
        float4 xv4 = xrow[k4];
        float xs[4] = {xv4.x, xv4.y, xv4.z, xv4.w};
        #pragma unroll
        for (int kk = 0; kk < 4; ++kk) {
            const float4* wr = (const float4*)(Wl + (k4 * 4 + kk) * 128 + hg * 16);
            float4 w0 = wr[0], w1 = wr[1], w2 = wr[2], w3 = wr[3];
            float xv = xs[kk];
            acc[0]  = fmaf(xv, w0.x, acc[0]);  acc[1]  = fmaf(xv, w0.y, acc[1]);
            acc[2]  = fmaf(xv, w0.z, acc[2]);  acc[3]  = fmaf(xv, w0.w, acc[3]);
            acc[4]  = fmaf(xv, w1.x, acc[4]);  acc[5]  = fmaf(xv, w1.y, acc[5]);
            acc[6]  = fmaf(xv, w1.z, acc[6]);  acc[7]  = fmaf(xv, w1.w, acc[7]);
            acc[8]  = fmaf(xv, w2.x, acc[8]);  acc[9]  = fmaf(xv, w2.y, acc[9]);
            acc[10] = fmaf(xv, w2.z, acc[10]); acc[11] = fmaf(xv, w2.w, acc[11]);
            acc[12] = fmaf(xv, w3.x, acc[12]); acc[13] = fmaf(xv, w3.y, acc[13]);
            acc[14] = fmaf(xv, w3.z, acc[14]); acc[15] = fmaf(xv, w3.w, acc[15]);
        }
    }

    float s_src = 0.f, s_dst = 0.f;
    const float* av = a_src + hg * 16;
    const float* bv = a_dst + hg * 16;
    #pragma unroll
    for (int j = 0; j < 16; ++j) {
        s_src = fmaf(acc[j], av[j], s_src);
        s_dst = fmaf(acc[j], bv[j], s_dst);
    }

    unsigned int pk[8];
    #pragma unroll
    for (int q = 0; q < 8; ++q) {
        unsigned int lo = rne_bf16(acc[2 * q]);
        unsigned int u  = __float_as_uint(acc[2 * q + 1]);
        unsigned int hi = (u + 0x7FFFu + ((u >> 16) & 1u)) & 0xFFFF0000u;
        pk[q] = lo | hi;
    }
    uint4* o = (uint4*)(h1b + (size_t)n * 64 + hg * 8);
    o[0] = make_uint4(pk[0], pk[1], pk[2], pk[3]);
    o[1] = make_uint4(pk[4], pk[5], pk[6], pk[7]);
    as1[n * 8 + hg] = s_src;
    ad1[n * 8 + hg] = s_dst;
}

// ==================== K2: layer-1 gather + fused layer-2 transform ====================
// One wave per dst. Unroll x8 (16 loads in flight) + unsigned 32-bit indexing so
// LLVM emits global_load with SGPR base + 32-bit voffset (1 lshl_add per load).
__global__ __launch_bounds__(256) void k_agg1(
    const int* __restrict__ csr, const int* __restrict__ cursor, const int* __restrict__ counts,
    const float* __restrict__ as1, const float* __restrict__ ad1,
    const unsigned int* __restrict__ h1b, const float* __restrict__ b1,
    const float* __restrict__ W2, const float* __restrict__ a2_src, const float* __restrict__ a2_dst,
    unsigned int* __restrict__ rec2, float* __restrict__ ad2, int N)
{
    const int d = (blockIdx.x * 256 + threadIdx.x) >> 6;   // one wave per destination
    if (d >= N) return;                                     // wave-uniform; no barriers below
    const int lane = threadIdx.x & 63;
    const int h = lane >> 3;
    const int deg = counts[d];
    const int start = cursor[d] - deg;   // cursor holds segment END after k_scatter

    const float myad = ad1[(unsigned)(d * 8 + h)];
    float acc0 = 0.f, acc1 = 0.f, wsum = 0.f;

    for (int base = 0; base < deg; base += 64) {
        int cnt = min(deg - base, 64);
        int lidx = lane < cnt ? lane : cnt - 1;
        int sj = csr[(unsigned)(start + base + lidx)];
        int j = 0;
        for (; j + 8 <= cnt; j += 8) {
            int ss[8];
            #pragma unroll
            for (int k = 0; k < 8; ++k) ss[k] = __shfl(sj, j + k);
            float ee[8];
            unsigned int uu[8];
            #pragma unroll
            for (int k = 0; k < 8; ++k) {
                ee[k] = as1[(unsigned)(ss[k] * 8 + h)];
                uu[k] = h1b[(unsigned)(ss[k] * 64 + lane)];
            }
            #pragma unroll
            for (int k = 0; k < 8; ++k) {
                float w = __expf(lrelu(ee[k] + myad, NEG_ATT));
                float2 v = bf2_to_f2(uu[k]);
                acc0 = fmaf(w, v.x, acc0);
                acc1 = fmaf(w, v.y, acc1);
                wsum += w;
            }
        }
        for (; j < cnt; ++j) {
            int s = __shfl(sj, j);
            float wgt = __expf(lrelu(as1[(unsigned)(s * 8 + h)] + myad, NEG_ATT));
            float2 hv = bf2_to_f2(h1b[(unsigned)(s * 64 + lane)]);
            acc0 = fmaf(wgt, hv.x, acc0);
            acc1 = fmaf(wgt, hv.y, acc1);
            wsum += wgt;
        }
    }

    // x2 row elements owned by this lane (channels 2*lane, 2*lane+1)
    float inv = 1.f / wsum;
    float2 bb = *(const float2*)(b1 + (unsigned)(lane * 2));
    float xa = lrelu(fmaf(acc0, inv, bb.x), NEG_ACT);
    float xb = lrelu(fmaf(acc1, inv, bb.y), NEG_ACT);

    // per-lane partial of h2[j] = sum_k x2[k]*W2[k][j]
    float pj[16];
    {
        const float4* wra = (const float4*)(W2 + (unsigned)(2 * lane) * 16u);
        const float4* wrb = (const float4*)(W2 + (unsigned)(2 * lane + 1) * 16u);
        #pragma unroll
        for (int q = 0; q < 4; ++q) {
            float4 wa = wra[q], wb = wrb[q];
            pj[q * 4 + 0] = fmaf(xa, wa.x, xb * wb.x);
            pj[q * 4 + 1] = fmaf(xa, wa.y, xb * wb.y);
            pj[q * 4 + 2] = fmaf(xa, wa.z, xb * wb.z);
            pj[q * 4 + 3] = fmaf(xa, wa.w, xb * wb.w);
        }
    }
    #pragma unroll
    for (int m = 1; m < 64; m <<= 1) {
        #pragma unroll
        for (int q = 0; q < 16; ++q) pj[q] += __shfl_xor(pj[q], m, 64);
    }
    float s_src = 0.f, s_dst = 0.f;
    #pragma unroll
    for (int q = 0; q < 4; ++q) {
        float4 av = ((const float4*)a2_src)[q];
        float4 dv = ((const float4*)a2_dst)[q];
        s_src += pj[q*4+0]*av.x + pj[q*4+1]*av.y + pj[q*4+2]*av.z + pj[q*4+3]*av.w;
        s_dst += pj[q*4+0]*dv.x + pj[q*4+1]*dv.y + pj[q*4+2]*dv.z + pj[q*4+3]*dv.w;
    }
    if (lane == 0) {
        // rec2[d]: 64-B record = h2 bf16[16] (32 B) | as2 f32 (4 B) | pad
        unsigned int pk[8];
        #pragma unroll
        for (int q = 0; q < 8; ++q) {
            unsigned int lo = rne_bf16(pj[2 * q]);
            unsigned int u  = __float_as_uint(pj[2 * q + 1]);
            unsigned int hi = (u + 0x7FFFu + ((u >> 16) & 1u)) & 0xFFFF0000u;
            pk[q] = lo | hi;
        }
        uint4* o = (uint4*)(rec2 + (size_t)d * 16);
        o[0] = make_uint4(pk[0], pk[1], pk[2], pk[3]);
        o[1] = make_uint4(pk[4], pk[5], pk[6], pk[7]);
        rec2[(size_t)d * 16 + 8] = __float_as_uint(s_src);
        ad2[d] = s_dst;
    }
}

// ==================== K3: layer-2 gather + bias + final softmax (16 lanes/dst) ==========
// Per edge: ONE 64-B line (rec2[s] holds h2 bf16 + as2). Unroll x8, unsigned offsets.
__global__ __launch_bounds__(256) void k_agg2(
    const int* __restrict__ csr, const int* __restrict__ cursor, const int* __restrict__ counts,
    const unsigned int* __restrict__ rec2, const float* __restrict__ ad2,
    const float* __restrict__ b2, float* __restrict__ out, int N)
{
    const int d = (blockIdx.x * 256 + threadIdx.x) >> 4;
    if (d >= N) return;
    const int j = threadIdx.x & 15;
    const int deg = counts[d];
    const int start = cursor[d] - deg;

    const float myad = ad2[d];
    float acc = 0.f, wsum = 0.f;
    for (int base = 0; base < deg; base += 16) {
        int cnt = min(deg - base, 16);
        int lidx = j < cnt ? j : cnt - 1;
        int sj = csr[(unsigned)(start + base + lidx)];
        int t = 0;
        for (; t + 8 <= cnt; t += 8) {
            int ss[8];
            #pragma unroll
            for (int k = 0; k < 8; ++k) ss[k] = __shfl(sj, t + k, 16);
            unsigned int pp[8];
            float ee[8];
            #pragma unroll
            for (int k = 0; k < 8; ++k) {
                unsigned int rbase = (unsigned)ss[k] * 16u;
                pp[k] = rec2[rbase + (unsigned)(j >> 1)];
                ee[k] = __uint_as_float(rec2[rbase + 8u]);
            }
            #pragma unroll
            for (int k = 0; k < 8; ++k) {
                float w = __expf(lrelu(ee[k] + myad, NEG_ATT));
                float v = __uint_as_float((j & 1) ? (pp[k] & 0xFFFF0000u) : (pp[k] << 16));
                acc = fmaf(w, v, acc);
                wsum += w;
            }
        }
        for (; t < cnt; ++t) {
            int s = __shfl(sj, t, 16);
            unsigned int rbase = (unsigned)s * 16u;
            unsigned int p = rec2[rbase + (unsigned)(j >> 1)];
            float v = __uint_as_float((j & 1) ? (p & 0xFFFF0000u) : (p << 16));
            float wgt = __expf(lrelu(__uint_as_float(rec2[rbase + 8u]) + myad, NEG_ATT));
            acc = fmaf(wgt, v, acc);
            wsum += wgt;
        }
    }
    float logit = acc / wsum + b2[j];
    float m = logit;
    #pragma unroll
    for (int s = 8; s >= 1; s >>= 1) m = fmaxf(m, __shfl_xor(m, s, 16));
    float ex = __expf(logit - m);
    float sum = ex;
    #pragma unroll
    for (int s = 8; s >= 1; s >>= 1) sum += __shfl_xor(sum, s, 16);
    out[(size_t)d * 16 + j] = ex / sum;
}

extern "C" void kernel_launch(void* const* d_in, const int* in_sizes, int n_in,
                              void* d_out, int out_size, void* d_ws, size_t ws_size,
                              hipStream_t stream)
{
    const float* x   = (const float*)d_in[0];
    const int*   ei  = (const int*)d_in[1];
    const float* W1  = (const float*)d_in[2];
    const float* a1s = (const float*)d_in[3];
    const float* a1d = (const float*)d_in[4];
    const float* b1  = (const float*)d_in[5];
    const float* W2  = (const float*)d_in[6];
    const float* a2s = (const float*)d_in[7];
    const float* a2d = (const float*)d_in[8];
    const float* b2  = (const float*)d_in[9];

    const int N = in_sizes[0] / 128;
    const int E = in_sizes[1] / 2;
    const int Etot = E + N;
    const int* srcp = ei;
    const int* dstp = ei + E;
    const int NB = (N + 1023) / 1024;

    // workspace layout (~47 MB)
    float* p = (float*)d_ws;
    unsigned int* h1b = (unsigned int*)p; p += (size_t)N * 64;   // bf16-packed h1
    float* as1 = p; p += (size_t)N * 8;
    float* ad1 = p; p += (size_t)N * 8;
    unsigned int* rec2 = (unsigned int*)p; p += (size_t)N * 16;  // h2(bf16)+as2 records
    float* ad2 = p; p += N;
    int* counts = (int*)p; p += N;
    int* cursor = (int*)p; p += N;
    int* csr    = (int*)p; p += Etot;
    int* bsum   = (int*)p; p += 1024;
    int* boff   = (int*)p; p += 1024;

    hipMemsetAsync(counts, 0, (size_t)N * sizeof(int), stream);

    k_hist   <<<(Etot + 255) / 256, 256, 0, stream>>>(dstp, counts, E, Etot);
    k_bsum   <<<NB, 1024, 0, stream>>>(counts, bsum, N);
    k_scan   <<<1, 1024, 0, stream>>>(bsum, boff, NB);
    k_scanadd<<<NB, 1024, 0, stream>>>(counts, boff, cursor, N);
    k_scatter<<<(Etot + 255) / 256, 256, 0, stream>>>(srcp, dstp, cursor, csr, E, Etot);
    k_gemm1  <<<(N + 31) / 32, 256, 0, stream>>>(x, W1, a1s, a1d, h1b, as1, ad1, N);
    k_agg1   <<<(N + 3) / 4, 256, 0, stream>>>(csr, cursor, counts, as1, ad1, h1b, b1,
                                               W2, a2s, a2d, rec2, ad2, N);
    k_agg2   <<<(N * 16 + 255) / 256, 256, 0, stream>>>(csr, cursor, counts, rec2, ad2, b2,
                                                        (float*)d_out, N);
}